// Round 20
// baseline (122.618 us; speedup 1.0000x reference)
//
#include <hip/hip_runtime.h>
#include <math.h>

#define L_ 64
#define HPf 1.57079632679489661923f
#define TIE_THR 4e-3f        // f16-split dot err ~2e-5 << fp32's 4e-4 bound

typedef _Float16 half4 __attribute__((ext_vector_type(4)));
typedef float    f32x4 __attribute__((ext_vector_type(4)));

// split fp32 vec4 -> f16 hi + f16 lo (x = hi + lo + O(2^-22 x))
#define CVT4(H, L, V) {                                                       \
    _Float16 h0=(_Float16)(V).x, h1=(_Float16)(V).y,                          \
             h2=(_Float16)(V).z, h3=(_Float16)(V).w;                          \
    (H) = (half4){h0, h1, h2, h3};                                            \
    (L) = (half4){(_Float16)((V).x-(float)h0), (_Float16)((V).y-(float)h1),   \
                  (_Float16)((V).z-(float)h2), (_Float16)((V).w-(float)h3)};  \
}
// hi-only f16 round (for value-only edge/center paths)
#define CVTH4(H, V) {                                                         \
    (H) = (half4){(_Float16)(V).x, (_Float16)(V).y,                           \
                  (_Float16)(V).z, (_Float16)(V).w};                          \
}

// support dots: same op order as R13-R19 -> bit-identical -> identical argmax
#define MFMA6T(ACC, T, M)                                                           \
    ACC = __builtin_amdgcn_mfma_f32_16x16x16f16(sh[T][0], nh[M][0], ACC, 0, 0, 0); \
    ACC = __builtin_amdgcn_mfma_f32_16x16x16f16(sh[T][0], nl[M][0], ACC, 0, 0, 0); \
    ACC = __builtin_amdgcn_mfma_f32_16x16x16f16(sl[T][0], nh[M][0], ACC, 0, 0, 0); \
    ACC = __builtin_amdgcn_mfma_f32_16x16x16f16(sh[T][1], nh[M][1], ACC, 0, 0, 0); \
    ACC = __builtin_amdgcn_mfma_f32_16x16x16f16(sh[T][1], nl[M][1], ACC, 0, 0, 0); \
    ACC = __builtin_amdgcn_mfma_f32_16x16x16f16(sl[T][1], nh[M][1], ACC, 0, 0, 0);

// A&S 4.4.49 minimax, |err| <= 1e-5 on [0,1]
__device__ __forceinline__ float atan_poly01(float t) {
    float t2 = t * t;
    float p = fmaf(t2, 0.0208351f, -0.0851330f);
    p = fmaf(t2, p, 0.1801410f);
    p = fmaf(t2, p, -0.3302995f);
    p = fmaf(t2, p, 0.9998660f);
    return t * p;
}
// atan(|x|)
__device__ __forceinline__ float fast_atan_abs(float x) {
    float ax = fabsf(x);
    float r  = __builtin_amdgcn_rcpf(ax);
    bool inv = ax > 1.0f;
    float p  = atan_poly01(inv ? r : ax);
    return inv ? (HPf - p) : p;
}
// atan(1/h), h > 0
__device__ __forceinline__ float fast_atan_recip(float h) {
    float r  = __builtin_amdgcn_rcpf(h);
    bool inv = h > 1.0f;
    float p  = atan_poly01(inv ? r : h);
    return inv ? p : (HPf - p);
}

// ---------------- Kernel P: per-l scalar table (64 threads) ----------------
__global__ __launch_bounds__(64)
void setconvP(const float* __restrict__ x_support,
              const float* __restrict__ edge_sup,
              const float* __restrict__ x_center,
              const float* __restrict__ p_support,
              float* __restrict__ table)
{
    const int l = threadIdx.x;
    if (l >= L_) return;

    const float* xs = x_support + (size_t)l * 96;
    double ssq = 0.0;
    for (int i = 0; i < 96; ++i) { double v = (double)xs[i]; ssq += v * v; }

    const float* es = edge_sup + (size_t)l * 24;
    float esq = 0.f;
    for (int i = 0; i < 24; ++i) esq = fmaf(es[i], es[i], esq);

    const float* xc = x_center + (size_t)l * 32;
    float csq = 0.f;
    for (int i = 0; i < 32; ++i) csq = fmaf(xc[i], xc[i], csq);

    float p0[3], p1[3], p2[3];
    for (int d = 0; d < 3; ++d) {
        p0[d] = p_support[(l * 3 + 0) * 3 + d];
        p1[d] = p_support[(l * 3 + 1) * 3 + d];
        p2[d] = p_support[(l * 3 + 2) * 3 + d];
    }
    float n0 = sqrtf(p0[0]*p0[0] + p0[1]*p0[1] + p0[2]*p0[2]);
    float n1 = sqrtf(p1[0]*p1[0] + p1[1]*p1[1] + p1[2]*p1[2]);
    float n2 = sqrtf(p2[0]*p2[0] + p2[1]*p2[1] + p2[2]*p2[2]);
    float d01 = p0[0]*p1[0] + p0[1]*p1[1] + p0[2]*p1[2];
    float d02 = p0[0]*p2[0] + p0[1]*p2[1] + p0[2]*p2[2];
    float d12 = p1[0]*p2[0] + p1[1]*p2[1] + p1[2]*p2[2];
    float C01 = d01 / fmaxf(n0 * n1, 1e-8f);
    float C02 = d02 / fmaxf(n0 * n2, 1e-8f);
    float C12 = d12 / fmaxf(n1 * n2, 1e-8f);

    float* t = table + l * 16;
    t[0] = n0;  t[1] = n1;  t[2] = n2;
    t[3] = C01; t[4] = C02; t[5] = C12;
    t[6] = C01*C01 + C02*C02 + C12*C12;
    t[7] = n0*n0 + n1*n1 + n2*n2;
    t[8] = esq;
    t[9] = csq;
    t[10] = (float)ssq;
}

// ------------- Kernel Pn: per-n p-geometry (lenN / angN), N threads --------
__global__ __launch_bounds__(256)
void setconvPn(const float* __restrict__ p_focal,
               const float* __restrict__ p_neighbor,
               float* __restrict__ nscal, int N)
{
    const int n = blockIdx.x * 256 + threadIdx.x;
    if (n >= N) return;
    float pf0 = p_focal[(size_t)n*3+0], pf1 = p_focal[(size_t)n*3+1], pf2 = p_focal[(size_t)n*3+2];
    const float* pp = p_neighbor + (size_t)n * 9;
    float pr00=pp[0]-pf0, pr01=pp[1]-pf1, pr02=pp[2]-pf2;
    float pr10=pp[3]-pf0, pr11=pp[4]-pf1, pr12=pp[5]-pf2;
    float pr20=pp[6]-pf0, pr21=pp[7]-pf1, pr22=pp[8]-pf2;
    float lenN0 = sqrtf(pr00*pr00 + pr01*pr01 + pr02*pr02);
    float lenN1 = sqrtf(pr10*pr10 + pr11*pr11 + pr12*pr12);
    float lenN2 = sqrtf(pr20*pr20 + pr21*pr21 + pr22*pr22);
    float angN0 = (pr20*pr00 + pr21*pr01 + pr22*pr02) / fmaxf(lenN2*lenN0, 1e-8f);
    float angN1 = (pr00*pr10 + pr01*pr11 + pr02*pr12) / fmaxf(lenN0*lenN1, 1e-8f);
    float angN2 = (pr10*pr20 + pr11*pr21 + pr12*pr22) / fmaxf(lenN1*lenN2, 1e-8f);
    f32x4 a = {lenN0, lenN1, lenN2, angN0};
    f32x4 b = {angN1, angN2,
               lenN0*lenN0 + lenN1*lenN1 + lenN2*lenN2,
               angN0*angN0 + angN1*angN1 + angN2*angN2};
    *(f32x4*)(nscal + (size_t)n * 8)     = a;
    *(f32x4*)(nscal + (size_t)n * 8 + 4) = b;
}

// ---------------- Kernel F (fused MFMA): ALL FIVE SCORES, final out ---------
// R19 with TWO 16-n chunks per wave: halves the per-cell cost of the A-side
// setup (~130 instr) while keeping the R17-style non-overlapping chunk loop
// (loads at top, consumed immediately -> no live-state inflation; R15/R18's
// overlap pattern is what blows VGPR). 12500 waves = 12/SIMD demand.
__global__ __launch_bounds__(64)
void setconvF(const float* __restrict__ x_neighbor,
              const float* __restrict__ x_support,
              const float* __restrict__ x_focal,
              const float* __restrict__ edge_nei,
              const float* __restrict__ x_center,
              const float* __restrict__ edge_sup,
              const float* __restrict__ table,
              const float* __restrict__ nscal,
              float* __restrict__ out,
              int* __restrict__ wl_cnt,
              int* __restrict__ wl,
              int wl_cap, int N)
{
    const int lane = threadIdx.x;
    const int j    = lane & 15;
    const int kg   = lane >> 4;
    const int l_w  = blockIdx.y * 16;        // l-quarter
    const int n_start = blockIdx.x * 32;     // x = n-block (dispatch-fastest)

    const float4 z4 = make_float4(0.f, 0.f, 0.f, 0.f);
    const f32x4  zf = {0.f, 0.f, 0.f, 0.f};

    // ---- A-side (per-l) fragments, loaded once per wave ----
    half4 sh[4][2], sl[4][2];          // support (hi+lo, ranking-critical)
    half4 esh[4];                      // edge (hi only)
    half4 xch[2];                      // center (hi only, permuted row map)
    {
        const int g = j >> 2, e = j & 3;
        #pragma unroll
        for (int t = 0; t < 4; ++t) {
            float4 v0 = z4, v1 = z4, ve = z4;
            if (e < 3) {
                const float* ap = x_support + (size_t)(l_w + 4*t + g) * 96 + e * 32 + kg * 4;
                v0 = *(const float4*)ap;
                v1 = *(const float4*)(ap + 16);
                if (kg < 2)
                    ve = *(const float4*)(edge_sup + (size_t)(l_w + 4*t + g) * 24 + e * 8 + kg * 4);
            }
            CVT4(sh[t][0], sl[t][0], v0);
            CVT4(sh[t][1], sl[t][1], v1);
            CVTH4(esh[t], ve);
        }
        const int l_c = l_w + 4 * (j & 3) + (j >> 2);
        #pragma unroll
        for (int h = 0; h < 2; ++h) {
            float4 v = *(const float4*)(x_center + (size_t)l_c * 32 + 16*h + kg * 4);
            CVTH4(xch[h], v);
        }
    }

    #pragma unroll 1
    for (int c = 0; c < 2; ++c) {
        const int n_j = n_start + c * 16 + j;
        const bool ok = (n_j < N);

        // ---- B-side (per-n) loads at chunk top (R17/R19 pattern) ----
        float4 w0h0=z4,w0h1=z4,w1h0=z4,w1h1=z4,w2h0=z4,w2h1=z4;
        float4 ef0=z4, ef1=z4, ef2=z4;
        float4 xf0=z4, xf1=z4;
        f32x4 ns0=zf, ns1=zf;
        if (ok) {
            const float* np = x_neighbor + (size_t)n_j * 96 + kg * 4;
            w0h0 = *(const float4*)(np +  0); w0h1 = *(const float4*)(np + 16);
            w1h0 = *(const float4*)(np + 32); w1h1 = *(const float4*)(np + 48);
            w2h0 = *(const float4*)(np + 64); w2h1 = *(const float4*)(np + 80);
            if (kg < 2) {
                const float* ep = edge_nei + (size_t)n_j * 24 + kg * 4;
                ef0 = *(const float4*)(ep +  0);
                ef1 = *(const float4*)(ep +  8);
                ef2 = *(const float4*)(ep + 16);
            }
            const float* fp = x_focal + (size_t)n_j * 32 + kg * 4;
            xf0 = *(const float4*)(fp + 0);
            xf1 = *(const float4*)(fp + 16);
            ns0 = *(const f32x4*)(nscal + (size_t)n_j * 8);
            ns1 = *(const f32x4*)(nscal + (size_t)n_j * 8 + 4);
        }

        // ---- sums (R13-R19 op order, bit-identical) ----
        float rp = 0.f;
        rp = fmaf(w0h0.x, w0h0.x, rp); rp = fmaf(w0h0.y, w0h0.y, rp);
        rp = fmaf(w0h0.z, w0h0.z, rp); rp = fmaf(w0h0.w, w0h0.w, rp);
        rp = fmaf(w0h1.x, w0h1.x, rp); rp = fmaf(w0h1.y, w0h1.y, rp);
        rp = fmaf(w0h1.z, w0h1.z, rp); rp = fmaf(w0h1.w, w0h1.w, rp);
        rp = fmaf(w1h0.x, w1h0.x, rp); rp = fmaf(w1h0.y, w1h0.y, rp);
        rp = fmaf(w1h0.z, w1h0.z, rp); rp = fmaf(w1h0.w, w1h0.w, rp);
        rp = fmaf(w1h1.x, w1h1.x, rp); rp = fmaf(w1h1.y, w1h1.y, rp);
        rp = fmaf(w1h1.z, w1h1.z, rp); rp = fmaf(w1h1.w, w1h1.w, rp);
        rp = fmaf(w2h0.x, w2h0.x, rp); rp = fmaf(w2h0.y, w2h0.y, rp);
        rp = fmaf(w2h0.z, w2h0.z, rp); rp = fmaf(w2h0.w, w2h0.w, rp);
        rp = fmaf(w2h1.x, w2h1.x, rp); rp = fmaf(w2h1.y, w2h1.y, rp);
        rp = fmaf(w2h1.z, w2h1.z, rp); rp = fmaf(w2h1.w, w2h1.w, rp);
        rp += __shfl_xor(rp, 16);
        rp += __shfl_xor(rp, 32);

        float edsq = 0.f;
        edsq = fmaf(ef0.x, ef0.x, edsq); edsq = fmaf(ef0.y, ef0.y, edsq);
        edsq = fmaf(ef0.z, ef0.z, edsq); edsq = fmaf(ef0.w, ef0.w, edsq);
        edsq = fmaf(ef1.x, ef1.x, edsq); edsq = fmaf(ef1.y, ef1.y, edsq);
        edsq = fmaf(ef1.z, ef1.z, edsq); edsq = fmaf(ef1.w, ef1.w, edsq);
        edsq = fmaf(ef2.x, ef2.x, edsq); edsq = fmaf(ef2.y, ef2.y, edsq);
        edsq = fmaf(ef2.z, ef2.z, edsq); edsq = fmaf(ef2.w, ef2.w, edsq);
        edsq += __shfl_xor(edsq, 16);
        edsq += __shfl_xor(edsq, 32);

        float xfsq = 0.f;
        xfsq = fmaf(xf0.x, xf0.x, xfsq); xfsq = fmaf(xf0.y, xf0.y, xfsq);
        xfsq = fmaf(xf0.z, xf0.z, xfsq); xfsq = fmaf(xf0.w, xf0.w, xfsq);
        xfsq = fmaf(xf1.x, xf1.x, xfsq); xfsq = fmaf(xf1.y, xf1.y, xfsq);
        xfsq = fmaf(xf1.z, xf1.z, xfsq); xfsq = fmaf(xf1.w, xf1.w, xfsq);
        xfsq += __shfl_xor(xfsq, 16);
        xfsq += __shfl_xor(xfsq, 32);

        const float lenN0 = ns0[0], lenN1 = ns0[1], lenN2 = ns0[2];
        const float angN0 = ns0[3], angN1 = ns1[0], angN2 = ns1[1];
        const float lenN_sq = ns1[2], angN_sq = ns1[3];

        // ---- B fragments: neighbor hi/lo (ranking), edge/focal hi only ----
        half4 nh[3][2], nl[3][2];
        CVT4(nh[0][0], nl[0][0], w0h0); CVT4(nh[0][1], nl[0][1], w0h1);
        CVT4(nh[1][0], nl[1][0], w1h0); CVT4(nh[1][1], nl[1][1], w1h1);
        CVT4(nh[2][0], nl[2][0], w2h0); CVT4(nh[2][1], nl[2][1], w2h1);
        half4 edh0, edh1, edh2;
        CVTH4(edh0, ef0); CVTH4(edh1, ef1); CVTH4(edh2, ef2);
        half4 xfh0, xfh1;
        CVTH4(xfh0, xf0); CVTH4(xfh1, xf1);

        // ---- center dots (single-pass) ----
        f32x4 accC = {};
        accC = __builtin_amdgcn_mfma_f32_16x16x16f16(xch[0], xfh0, accC, 0, 0, 0);
        accC = __builtin_amdgcn_mfma_f32_16x16x16f16(xch[1], xfh1, accC, 0, 0, 0);

        #pragma unroll
        for (int t = 0; t < 4; ++t) {
            const int l_t = l_w + 4*t + kg;
            const float* tb = table + l_t * 16;
            f32x4 tb0 = *(const f32x4*)tb;
            f32x4 tb1 = *(const f32x4*)(tb + 4);
            f32x4 tb2 = *(const f32x4*)(tb + 8);

            // support: 18 MFMAs (bit-identical order to R13-R19)
            f32x4 a0 = {}, a1 = {}, a2 = {};
            MFMA6T(a0, t, 0)
            MFMA6T(a1, t, 1)
            MFMA6T(a2, t, 2)

            // edge: 3 single-pass MFMAs (value-only)
            f32x4 e0 = {}, e1 = {}, e2 = {};
            e0 = __builtin_amdgcn_mfma_f32_16x16x16f16(esh[t], edh0, e0, 0, 0, 0);
            e1 = __builtin_amdgcn_mfma_f32_16x16x16f16(esh[t], edh1, e1, 0, 0, 0);
            e2 = __builtin_amdgcn_mfma_f32_16x16x16f16(esh[t], edh2, e2, 0, 0, 0);

            // perm sums (same order as R13-R19)
            float c0 = a0[0] + a1[1] + a2[2];   // (0,1,2) -> 6
            float c1 = a0[0] + a1[2] + a2[1];   // (0,2,1) -> 9
            float c2 = a0[1] + a1[0] + a2[2];   // (1,0,2) -> 18
            float c3 = a0[1] + a1[2] + a2[0];   // (1,2,0) -> 24
            float c4 = a0[2] + a1[0] + a2[1];   // (2,0,1) -> 33
            float c5 = a0[2] + a1[1] + a2[0];   // (2,1,0) -> 36

            float b1 = c0, b2 = -3.4e38f; int bpk = 6;
            if (c1 > b1) { b2 = b1; b1 = c1; bpk = 9;  } else if (c1 > b2) b2 = c1;
            if (c2 > b1) { b2 = b1; b1 = c2; bpk = 18; } else if (c2 > b2) b2 = c2;
            if (c3 > b1) { b2 = b1; b1 = c3; bpk = 24; } else if (c3 > b2) b2 = c3;
            if (c4 > b1) { b2 = b1; b1 = c4; bpk = 33; } else if (c4 > b2) b2 = c4;
            if (c5 > b1) { b2 = b1; b1 = c5; bpk = 36; } else if (c5 > b2) b2 = c5;

            const int a = (bpk >> 4) & 3, b = (bpk >> 2) & 3, cc = bpk & 3;

            float se0 = (a  == 0) ? e0[0] : ((a  == 1) ? e0[1] : e0[2]);
            float se1 = (b  == 0) ? e1[0] : ((b  == 1) ? e1[1] : e1[2]);
            float se2 = (cc == 0) ? e2[0] : ((cc == 1) ? e2[1] : e2[2]);
            float bestE = se0 + se1 + se2;

            float la = (a  == 0) ? tb0[0] : ((a  == 1) ? tb0[1] : tb0[2]);
            float lb = (b  == 0) ? tb0[0] : ((b  == 1) ? tb0[1] : tb0[2]);
            float lc = (cc == 0) ? tb0[0] : ((cc == 1) ? tb0[1] : tb0[2]);
            float bestL = fmaf(lenN0, la, fmaf(lenN1, lb, lenN2 * lc));

            float C01 = tb0[3], C02 = tb1[0], C12 = tb1[1];
            int sca = cc + a, sab = a + b, sbc = b + cc;          // in {1,2,3}
            float Cca = (sca == 1) ? C01 : ((sca == 2) ? C02 : C12);
            float Cab = (sab == 1) ? C01 : ((sab == 2) ? C02 : C12);
            float Cbc = (sbc == 1) ? C01 : ((sbc == 2) ? C02 : C12);
            float bestA = fmaf(angN0, Cca, fmaf(angN1, Cab, angN2 * Cbc));

            // atan(1/d) - pi/2 = -atan(d) for d>=0: squares equal
            float dist = rp + tb2[2] - 2.0f * b1;
            float t3v = fast_atan_abs(dist);
            float t1v = fast_atan_abs(lenN_sq + tb1[3] - 2.0f * bestL);
            float t2v = fast_atan_abs(angN_sq + tb1[2] - 2.0f * bestA);
            float t4v = fast_atan_abs(xfsq    + tb2[1] - 2.0f * accC[t]);
            float t5v = fast_atan_abs(edsq    + tb2[0] - 2.0f * bestE);

            float h = t1v*t1v + t2v*t2v + t3v*t3v + t4v*t4v + t5v*t5v;

            if (ok) {
                size_t idx = (size_t)l_t * N + n_j;
                out[idx] = fast_atan_recip(h);
                if (b1 - b2 <= TIE_THR) {
                    int slot = atomicAdd(wl_cnt, 1);
                    if (slot < wl_cap) wl[slot] = (int)idx;
                }
            }
        }
    }
}

// -------- Kernel A2: full recompute for tie cells (fp64 ranking) -----------
__global__ __launch_bounds__(256)
void setconvA2(const float* __restrict__ x_neighbor,
               const float* __restrict__ x_support,
               const float* __restrict__ x_focal,
               const float* __restrict__ p_focal,
               const float* __restrict__ p_neighbor,
               const float* __restrict__ edge_nei,
               const float* __restrict__ x_center,
               const float* __restrict__ edge_sup,
               const float* __restrict__ table,
               float* __restrict__ out,
               const int* __restrict__ wl_cnt,
               const int* __restrict__ wl,
               int wl_cap, int N)
{
    int cnt = *wl_cnt; if (cnt > wl_cap) cnt = wl_cap;
    const int stride = gridDim.x * blockDim.x;
    for (int i = blockIdx.x * blockDim.x + threadIdx.x; i < cnt; i += stride) {
        const int idx = wl[i];
        const int l = idx / N;
        const int n = idx - l * N;
        const float* xn = x_neighbor + (size_t)n * 96;
        const float* xs = x_support  + (size_t)l * 96;

        double dr[3][3] = {{0,0,0},{0,0,0},{0,0,0}};
        double nei = 0.0;
        for (int f = 0; f < 32; ++f) {
            double a0 = (double)xn[f], a1 = (double)xn[32 + f], a2 = (double)xn[64 + f];
            double b0 = (double)xs[f], b1 = (double)xs[32 + f], b2 = (double)xs[64 + f];
            dr[0][0] += a0 * b0; dr[0][1] += a0 * b1; dr[0][2] += a0 * b2;
            dr[1][0] += a1 * b0; dr[1][1] += a1 * b1; dr[1][2] += a1 * b2;
            dr[2][0] += a2 * b0; dr[2][1] += a2 * b1; dr[2][2] += a2 * b2;
            nei += a0 * a0 + a1 * a1 + a2 * a2;
        }
        double d0 = dr[0][0] + dr[1][1] + dr[2][2];
        double d1 = dr[0][0] + dr[1][2] + dr[2][1];
        double d2 = dr[0][1] + dr[1][0] + dr[2][2];
        double d3 = dr[0][1] + dr[1][2] + dr[2][0];
        double d4 = dr[0][2] + dr[1][0] + dr[2][1];
        double d5 = dr[0][2] + dr[1][1] + dr[2][0];
        double db = d0; int bpk = 6;
        if (d1 > db) { db = d1; bpk = 9;  }
        if (d2 > db) { db = d2; bpk = 18; }
        if (d3 > db) { db = d3; bpk = 24; }
        if (d4 > db) { db = d4; bpk = 33; }
        if (d5 > db) { db = d5; bpk = 36; }
        const int a = (bpk >> 4) & 3, b = (bpk >> 2) & 3, c = bpk & 3;

        const float* tb = table + l * 16;
        float dist = (float)(nei + (double)tb[10] - 2.0 * db);
        float t3v = atanf(dist);

        const float* es = edge_sup + (size_t)l * 24;
        const float* ed = edge_nei + (size_t)n * 24;
        float er[3][3] = {{0,0,0},{0,0,0},{0,0,0}};
        for (int f = 0; f < 8; ++f) {
            float b0 = es[f], b1 = es[8 + f], b2 = es[16 + f];
            float a0 = ed[f], a1 = ed[8 + f], a2 = ed[16 + f];
            er[0][0] = fmaf(a0, b0, er[0][0]);
            er[0][1] = fmaf(a0, b1, er[0][1]);
            er[0][2] = fmaf(a0, b2, er[0][2]);
            er[1][0] = fmaf(a1, b0, er[1][0]);
            er[1][1] = fmaf(a1, b1, er[1][1]);
            er[1][2] = fmaf(a1, b2, er[1][2]);
            er[2][0] = fmaf(a2, b0, er[2][0]);
            er[2][1] = fmaf(a2, b1, er[2][1]);
            er[2][2] = fmaf(a2, b2, er[2][2]);
        }
        float edsq = 0.f;
        for (int f = 0; f < 24; ++f) edsq = fmaf(ed[f], ed[f], edsq);

        const float* xf = x_focal + (size_t)n * 32;
        const float* xc = x_center + (size_t)l * 32;
        float cdot = 0.f, xfsq = 0.f;
        for (int f = 0; f < 32; ++f) {
            cdot = fmaf(xf[f], xc[f], cdot);
            xfsq = fmaf(xf[f], xf[f], xfsq);
        }

        float pf0 = p_focal[(size_t)n*3+0], pf1 = p_focal[(size_t)n*3+1], pf2 = p_focal[(size_t)n*3+2];
        const float* pp = p_neighbor + (size_t)n * 9;
        float pr00=pp[0]-pf0, pr01=pp[1]-pf1, pr02=pp[2]-pf2;
        float pr10=pp[3]-pf0, pr11=pp[4]-pf1, pr12=pp[5]-pf2;
        float pr20=pp[6]-pf0, pr21=pp[7]-pf1, pr22=pp[8]-pf2;
        float lenN0 = sqrtf(pr00*pr00 + pr01*pr01 + pr02*pr02);
        float lenN1 = sqrtf(pr10*pr10 + pr11*pr11 + pr12*pr12);
        float lenN2 = sqrtf(pr20*pr20 + pr21*pr21 + pr22*pr22);
        float angN0 = (pr20*pr00 + pr21*pr01 + pr22*pr02) / fmaxf(lenN2*lenN0, 1e-8f);
        float angN1 = (pr00*pr10 + pr01*pr11 + pr02*pr12) / fmaxf(lenN0*lenN1, 1e-8f);
        float angN2 = (pr10*pr20 + pr11*pr21 + pr12*pr22) / fmaxf(lenN1*lenN2, 1e-8f);
        float angN_sq = angN0*angN0 + angN1*angN1 + angN2*angN2;
        float lenN_sq = lenN0*lenN0 + lenN1*lenN1 + lenN2*lenN2;

        float bestE = er[0][a] + er[1][b] + er[2][c];
        float nv[3] = {tb[0], tb[1], tb[2]};
        float bestL = fmaf(lenN0, nv[a], fmaf(lenN1, nv[b], lenN2 * nv[c]));
        float C01 = tb[3], C02 = tb[4], C12 = tb[5];
        int sca = c + a, sab = a + b, sbc = b + c;
        float Cca = (sca == 1) ? C01 : ((sca == 2) ? C02 : C12);
        float Cab = (sab == 1) ? C01 : ((sab == 2) ? C02 : C12);
        float Cbc = (sbc == 1) ? C01 : ((sbc == 2) ? C02 : C12);
        float bestA = fmaf(angN0, Cca, fmaf(angN1, Cab, angN2 * Cbc));

        float t1v = atanf(lenN_sq + tb[7] - 2.0f * bestL);
        float t2v = atanf(angN_sq + tb[6] - 2.0f * bestA);
        float t4v = atanf(xfsq    + tb[9] - 2.0f * cdot);
        float t5v = atanf(edsq    + tb[8] - 2.0f * bestE);

        float h = t1v*t1v + t2v*t2v + t3v*t3v + t4v*t4v + t5v*t5v;
        out[idx] = atanf(1.0f / h);
    }
}

extern "C" void kernel_launch(void* const* d_in, const int* in_sizes, int n_in,
                              void* d_out, int out_size, void* d_ws, size_t ws_size,
                              hipStream_t stream)
{
    const float* x_focal    = (const float*)d_in[0];
    const float* p_focal    = (const float*)d_in[1];
    const float* x_neighbor = (const float*)d_in[2];
    const float* p_neighbor = (const float*)d_in[3];
    const float* edge_nei   = (const float*)d_in[4];
    const float* x_center   = (const float*)d_in[5];
    const float* x_support  = (const float*)d_in[6];
    const float* edge_sup   = (const float*)d_in[7];
    const float* p_support  = (const float*)d_in[8];
    float* out = (float*)d_out;

    const int N = in_sizes[0] / 32;                // x_focal is (N, 32)

    // d_ws layout: [0,4096) table | [4096, 4096+32N) nscal | cnt | worklist
    float* table = (float*)d_ws;
    float* nscal = (float*)((char*)d_ws + 4096);
    size_t cnt_off = 4096 + (size_t)N * 32;
    cnt_off = (cnt_off + 15) & ~(size_t)15;
    int* wl_cnt = (int*)((char*)d_ws + cnt_off);
    int* wl     = (int*)((char*)d_ws + cnt_off + 16);
    long cap_l = ((long)ws_size - (long)cnt_off - 16) / 4;
    int wl_cap = cap_l < 0 ? 0 : (cap_l > 4000000 ? 4000000 : (int)cap_l);

    hipMemsetAsync(wl_cnt, 0, sizeof(int), stream);

    setconvP<<<1, 64, 0, stream>>>(x_support, edge_sup, x_center, p_support, table);
    setconvPn<<<(N + 255) / 256, 256, 0, stream>>>(p_focal, p_neighbor, nscal, N);

    dim3 gridF((N + 31) / 32, 4);
    setconvF<<<gridF, 64, 0, stream>>>(x_neighbor, x_support, x_focal,
                                       edge_nei, x_center, edge_sup,
                                       table, nscal, out, wl_cnt, wl, wl_cap, N);
    setconvA2<<<64, 256, 0, stream>>>(x_neighbor, x_support, x_focal, p_focal,
                                      p_neighbor, edge_nei, x_center, edge_sup,
                                      table, out, wl_cnt, wl, wl_cap, N);
}

// Round 21
// 111.726 us; speedup vs baseline: 1.0975x; 1.0975x over previous
//
#include <hip/hip_runtime.h>
#include <math.h>

#define L_ 64
#define HPf 1.57079632679489661923f
#define TIE_THR 4e-3f        // f16-split dot err ~2e-5 << fp32's 4e-4 bound

typedef _Float16 half4 __attribute__((ext_vector_type(4)));
typedef float    f32x4 __attribute__((ext_vector_type(4)));

// split fp32 vec4 -> f16 hi + f16 lo (x = hi + lo + O(2^-22 x))
#define CVT4(H, L, V) {                                                       \
    _Float16 h0=(_Float16)(V).x, h1=(_Float16)(V).y,                          \
             h2=(_Float16)(V).z, h3=(_Float16)(V).w;                          \
    (H) = (half4){h0, h1, h2, h3};                                            \
    (L) = (half4){(_Float16)((V).x-(float)h0), (_Float16)((V).y-(float)h1),   \
                  (_Float16)((V).z-(float)h2), (_Float16)((V).w-(float)h3)};  \
}
// hi-only f16 round (for value-only edge/center paths)
#define CVTH4(H, V) {                                                         \
    (H) = (half4){(_Float16)(V).x, (_Float16)(V).y,                           \
                  (_Float16)(V).z, (_Float16)(V).w};                          \
}

// support dots: same op order as R13-R19 -> bit-identical -> identical argmax
#define MFMA6T(ACC, T, M)                                                           \
    ACC = __builtin_amdgcn_mfma_f32_16x16x16f16(sh[T][0], nh[M][0], ACC, 0, 0, 0); \
    ACC = __builtin_amdgcn_mfma_f32_16x16x16f16(sh[T][0], nl[M][0], ACC, 0, 0, 0); \
    ACC = __builtin_amdgcn_mfma_f32_16x16x16f16(sl[T][0], nh[M][0], ACC, 0, 0, 0); \
    ACC = __builtin_amdgcn_mfma_f32_16x16x16f16(sh[T][1], nh[M][1], ACC, 0, 0, 0); \
    ACC = __builtin_amdgcn_mfma_f32_16x16x16f16(sh[T][1], nl[M][1], ACC, 0, 0, 0); \
    ACC = __builtin_amdgcn_mfma_f32_16x16x16f16(sl[T][1], nh[M][1], ACC, 0, 0, 0);

// A&S 4.4.49 minimax, |err| <= 1e-5 on [0,1]
__device__ __forceinline__ float atan_poly01(float t) {
    float t2 = t * t;
    float p = fmaf(t2, 0.0208351f, -0.0851330f);
    p = fmaf(t2, p, 0.1801410f);
    p = fmaf(t2, p, -0.3302995f);
    p = fmaf(t2, p, 0.9998660f);
    return t * p;
}
// atan(|x|)
__device__ __forceinline__ float fast_atan_abs(float x) {
    float ax = fabsf(x);
    float r  = __builtin_amdgcn_rcpf(ax);
    bool inv = ax > 1.0f;
    float p  = atan_poly01(inv ? r : ax);
    return inv ? (HPf - p) : p;
}
// atan(1/h), h > 0
__device__ __forceinline__ float fast_atan_recip(float h) {
    float r  = __builtin_amdgcn_rcpf(h);
    bool inv = h > 1.0f;
    float p  = atan_poly01(inv ? r : h);
    return inv ? p : (HPf - p);
}

// ------- Kernel PP: per-n p-geometry + (block 0) per-l table + cnt reset ----
// nscal[n*8 + ..] = {lenN0,lenN1,lenN2,angN0, angN1,angN2,lenN_sq,angN_sq}
// table row l (16 floats): [0]n0 [1]n1 [2]n2 [3]C01 [4]C02 [5]C12
//                          [6]angS_sq [7]lenS_sq [8]esq [9]csq [10]ssqf
__global__ __launch_bounds__(256)
void setconvPP(const float* __restrict__ p_focal,
               const float* __restrict__ p_neighbor,
               const float* __restrict__ x_support,
               const float* __restrict__ edge_sup,
               const float* __restrict__ x_center,
               const float* __restrict__ p_support,
               float* __restrict__ nscal,
               float* __restrict__ table,
               int* __restrict__ wl_cnt,
               int N)
{
    const int tid = threadIdx.x;
    const int n = blockIdx.x * 256 + tid;

    if (n < N) {
        float pf0 = p_focal[(size_t)n*3+0], pf1 = p_focal[(size_t)n*3+1], pf2 = p_focal[(size_t)n*3+2];
        const float* pp = p_neighbor + (size_t)n * 9;
        float pr00=pp[0]-pf0, pr01=pp[1]-pf1, pr02=pp[2]-pf2;
        float pr10=pp[3]-pf0, pr11=pp[4]-pf1, pr12=pp[5]-pf2;
        float pr20=pp[6]-pf0, pr21=pp[7]-pf1, pr22=pp[8]-pf2;
        float lenN0 = sqrtf(pr00*pr00 + pr01*pr01 + pr02*pr02);
        float lenN1 = sqrtf(pr10*pr10 + pr11*pr11 + pr12*pr12);
        float lenN2 = sqrtf(pr20*pr20 + pr21*pr21 + pr22*pr22);
        float angN0 = (pr20*pr00 + pr21*pr01 + pr22*pr02) / fmaxf(lenN2*lenN0, 1e-8f);
        float angN1 = (pr00*pr10 + pr01*pr11 + pr02*pr12) / fmaxf(lenN0*lenN1, 1e-8f);
        float angN2 = (pr10*pr20 + pr11*pr21 + pr12*pr22) / fmaxf(lenN1*lenN2, 1e-8f);
        f32x4 a = {lenN0, lenN1, lenN2, angN0};
        f32x4 b = {angN1, angN2,
                   lenN0*lenN0 + lenN1*lenN1 + lenN2*lenN2,
                   angN0*angN0 + angN1*angN1 + angN2*angN2};
        *(f32x4*)(nscal + (size_t)n * 8)     = a;
        *(f32x4*)(nscal + (size_t)n * 8 + 4) = b;
    }

    if (blockIdx.x == 0) {
        if (tid == 255) *wl_cnt = 0;     // replaces hipMemsetAsync dispatch
        if (tid < L_) {
            const int l = tid;
            const float* xs = x_support + (size_t)l * 96;
            double ssq = 0.0;
            for (int i = 0; i < 96; ++i) { double v = (double)xs[i]; ssq += v * v; }

            const float* es = edge_sup + (size_t)l * 24;
            float esq = 0.f;
            for (int i = 0; i < 24; ++i) esq = fmaf(es[i], es[i], esq);

            const float* xc = x_center + (size_t)l * 32;
            float csq = 0.f;
            for (int i = 0; i < 32; ++i) csq = fmaf(xc[i], xc[i], csq);

            float p0[3], p1[3], p2[3];
            for (int d = 0; d < 3; ++d) {
                p0[d] = p_support[(l * 3 + 0) * 3 + d];
                p1[d] = p_support[(l * 3 + 1) * 3 + d];
                p2[d] = p_support[(l * 3 + 2) * 3 + d];
            }
            float n0 = sqrtf(p0[0]*p0[0] + p0[1]*p0[1] + p0[2]*p0[2]);
            float n1 = sqrtf(p1[0]*p1[0] + p1[1]*p1[1] + p1[2]*p1[2]);
            float n2 = sqrtf(p2[0]*p2[0] + p2[1]*p2[1] + p2[2]*p2[2]);
            float d01 = p0[0]*p1[0] + p0[1]*p1[1] + p0[2]*p1[2];
            float d02 = p0[0]*p2[0] + p0[1]*p2[1] + p0[2]*p2[2];
            float d12 = p1[0]*p2[0] + p1[1]*p2[1] + p1[2]*p2[2];
            float C01 = d01 / fmaxf(n0 * n1, 1e-8f);
            float C02 = d02 / fmaxf(n0 * n2, 1e-8f);
            float C12 = d12 / fmaxf(n1 * n2, 1e-8f);

            float* t = table + l * 16;
            t[0] = n0;  t[1] = n1;  t[2] = n2;
            t[3] = C01; t[4] = C02; t[5] = C12;
            t[6] = C01*C01 + C02*C02 + C12*C12;
            t[7] = n0*n0 + n1*n1 + n2*n2;
            t[8] = esq;
            t[9] = csq;
            t[10] = (float)ssq;
        }
    }
}

// ---------------- Kernel F (fused MFMA): EXACT R19 (best measured) ----------
// ONE 16n x 16l chunk per wave: 25000 waves = 24/SIMD demand, VGPR 80 ->
// occupancy 30%, VALUBusy 63%. R15/R18 proved in-wave pipelining inflates
// VGPR; R20 proved a 2-chunk loop re-inflates to 104. This is the optimum.
__global__ __launch_bounds__(64)
void setconvF(const float* __restrict__ x_neighbor,
              const float* __restrict__ x_support,
              const float* __restrict__ x_focal,
              const float* __restrict__ edge_nei,
              const float* __restrict__ x_center,
              const float* __restrict__ edge_sup,
              const float* __restrict__ table,
              const float* __restrict__ nscal,
              float* __restrict__ out,
              int* __restrict__ wl_cnt,
              int* __restrict__ wl,
              int wl_cap, int N)
{
    const int lane = threadIdx.x;
    const int j    = lane & 15;
    const int kg   = lane >> 4;
    const int l_w  = blockIdx.y * 16;        // l-quarter
    const int n_j  = blockIdx.x * 16 + j;    // x = n-chunk (dispatch-fastest)
    const bool ok  = (n_j < N);

    const float4 z4 = make_float4(0.f, 0.f, 0.f, 0.f);
    const f32x4  zf = {0.f, 0.f, 0.f, 0.f};

    // ---- B-side (per-n) loads: issue FIRST (longest latency) ----
    float4 w0h0=z4,w0h1=z4,w1h0=z4,w1h1=z4,w2h0=z4,w2h1=z4;
    float4 ef0=z4, ef1=z4, ef2=z4;
    float4 xf0=z4, xf1=z4;
    f32x4 ns0=zf, ns1=zf;
    if (ok) {
        const float* np = x_neighbor + (size_t)n_j * 96 + kg * 4;
        w0h0 = *(const float4*)(np +  0); w0h1 = *(const float4*)(np + 16);
        w1h0 = *(const float4*)(np + 32); w1h1 = *(const float4*)(np + 48);
        w2h0 = *(const float4*)(np + 64); w2h1 = *(const float4*)(np + 80);
        if (kg < 2) {
            const float* ep = edge_nei + (size_t)n_j * 24 + kg * 4;
            ef0 = *(const float4*)(ep +  0);
            ef1 = *(const float4*)(ep +  8);
            ef2 = *(const float4*)(ep + 16);
        }
        const float* fp = x_focal + (size_t)n_j * 32 + kg * 4;
        xf0 = *(const float4*)(fp + 0);
        xf1 = *(const float4*)(fp + 16);
        ns0 = *(const f32x4*)(nscal + (size_t)n_j * 8);
        ns1 = *(const f32x4*)(nscal + (size_t)n_j * 8 + 4);
    }

    // ---- A-side (per-l) fragments ----
    half4 sh[4][2], sl[4][2];          // support (hi+lo, ranking-critical)
    half4 esh[4];                      // edge (hi only)
    half4 xch[2];                      // center (hi only, permuted row map)
    {
        const int g = j >> 2, e = j & 3;
        #pragma unroll
        for (int t = 0; t < 4; ++t) {
            float4 v0 = z4, v1 = z4, ve = z4;
            if (e < 3) {
                const float* ap = x_support + (size_t)(l_w + 4*t + g) * 96 + e * 32 + kg * 4;
                v0 = *(const float4*)ap;
                v1 = *(const float4*)(ap + 16);
                if (kg < 2)
                    ve = *(const float4*)(edge_sup + (size_t)(l_w + 4*t + g) * 24 + e * 8 + kg * 4);
            }
            CVT4(sh[t][0], sl[t][0], v0);
            CVT4(sh[t][1], sl[t][1], v1);
            CVTH4(esh[t], ve);
        }
        const int l_c = l_w + 4 * (j & 3) + (j >> 2);
        #pragma unroll
        for (int h = 0; h < 2; ++h) {
            float4 v = *(const float4*)(x_center + (size_t)l_c * 32 + 16*h + kg * 4);
            CVTH4(xch[h], v);
        }
    }

    // ---- sums (R13-R19 op order, bit-identical) ----
    float rp = 0.f;
    rp = fmaf(w0h0.x, w0h0.x, rp); rp = fmaf(w0h0.y, w0h0.y, rp);
    rp = fmaf(w0h0.z, w0h0.z, rp); rp = fmaf(w0h0.w, w0h0.w, rp);
    rp = fmaf(w0h1.x, w0h1.x, rp); rp = fmaf(w0h1.y, w0h1.y, rp);
    rp = fmaf(w0h1.z, w0h1.z, rp); rp = fmaf(w0h1.w, w0h1.w, rp);
    rp = fmaf(w1h0.x, w1h0.x, rp); rp = fmaf(w1h0.y, w1h0.y, rp);
    rp = fmaf(w1h0.z, w1h0.z, rp); rp = fmaf(w1h0.w, w1h0.w, rp);
    rp = fmaf(w1h1.x, w1h1.x, rp); rp = fmaf(w1h1.y, w1h1.y, rp);
    rp = fmaf(w1h1.z, w1h1.z, rp); rp = fmaf(w1h1.w, w1h1.w, rp);
    rp = fmaf(w2h0.x, w2h0.x, rp); rp = fmaf(w2h0.y, w2h0.y, rp);
    rp = fmaf(w2h0.z, w2h0.z, rp); rp = fmaf(w2h0.w, w2h0.w, rp);
    rp = fmaf(w2h1.x, w2h1.x, rp); rp = fmaf(w2h1.y, w2h1.y, rp);
    rp = fmaf(w2h1.z, w2h1.z, rp); rp = fmaf(w2h1.w, w2h1.w, rp);
    rp += __shfl_xor(rp, 16);
    rp += __shfl_xor(rp, 32);

    float edsq = 0.f;
    edsq = fmaf(ef0.x, ef0.x, edsq); edsq = fmaf(ef0.y, ef0.y, edsq);
    edsq = fmaf(ef0.z, ef0.z, edsq); edsq = fmaf(ef0.w, ef0.w, edsq);
    edsq = fmaf(ef1.x, ef1.x, edsq); edsq = fmaf(ef1.y, ef1.y, edsq);
    edsq = fmaf(ef1.z, ef1.z, edsq); edsq = fmaf(ef1.w, ef1.w, edsq);
    edsq = fmaf(ef2.x, ef2.x, edsq); edsq = fmaf(ef2.y, ef2.y, edsq);
    edsq = fmaf(ef2.z, ef2.z, edsq); edsq = fmaf(ef2.w, ef2.w, edsq);
    edsq += __shfl_xor(edsq, 16);
    edsq += __shfl_xor(edsq, 32);

    float xfsq = 0.f;
    xfsq = fmaf(xf0.x, xf0.x, xfsq); xfsq = fmaf(xf0.y, xf0.y, xfsq);
    xfsq = fmaf(xf0.z, xf0.z, xfsq); xfsq = fmaf(xf0.w, xf0.w, xfsq);
    xfsq = fmaf(xf1.x, xf1.x, xfsq); xfsq = fmaf(xf1.y, xf1.y, xfsq);
    xfsq = fmaf(xf1.z, xf1.z, xfsq); xfsq = fmaf(xf1.w, xf1.w, xfsq);
    xfsq += __shfl_xor(xfsq, 16);
    xfsq += __shfl_xor(xfsq, 32);

    const float lenN0 = ns0[0], lenN1 = ns0[1], lenN2 = ns0[2];
    const float angN0 = ns0[3], angN1 = ns1[0], angN2 = ns1[1];
    const float lenN_sq = ns1[2], angN_sq = ns1[3];

    // ---- B fragments: neighbor hi/lo (ranking), edge/focal hi only ----
    half4 nh[3][2], nl[3][2];
    CVT4(nh[0][0], nl[0][0], w0h0); CVT4(nh[0][1], nl[0][1], w0h1);
    CVT4(nh[1][0], nl[1][0], w1h0); CVT4(nh[1][1], nl[1][1], w1h1);
    CVT4(nh[2][0], nl[2][0], w2h0); CVT4(nh[2][1], nl[2][1], w2h1);
    half4 edh0, edh1, edh2;
    CVTH4(edh0, ef0); CVTH4(edh1, ef1); CVTH4(edh2, ef2);
    half4 xfh0, xfh1;
    CVTH4(xfh0, xf0); CVTH4(xfh1, xf1);

    // ---- center dots (single-pass): accC[t] = cdot for (n_j, l_w+4t+kg) ----
    f32x4 accC = {};
    accC = __builtin_amdgcn_mfma_f32_16x16x16f16(xch[0], xfh0, accC, 0, 0, 0);
    accC = __builtin_amdgcn_mfma_f32_16x16x16f16(xch[1], xfh1, accC, 0, 0, 0);

    #pragma unroll
    for (int t = 0; t < 4; ++t) {
        const int l_t = l_w + 4*t + kg;
        const float* tb = table + l_t * 16;
        f32x4 tb0 = *(const f32x4*)tb;
        f32x4 tb1 = *(const f32x4*)(tb + 4);
        f32x4 tb2 = *(const f32x4*)(tb + 8);

        // support: 18 MFMAs (bit-identical order to R13-R19)
        f32x4 a0 = {}, a1 = {}, a2 = {};
        MFMA6T(a0, t, 0)
        MFMA6T(a1, t, 1)
        MFMA6T(a2, t, 2)

        // edge: 3 single-pass MFMAs (value-only)
        f32x4 e0 = {}, e1 = {}, e2 = {};
        e0 = __builtin_amdgcn_mfma_f32_16x16x16f16(esh[t], edh0, e0, 0, 0, 0);
        e1 = __builtin_amdgcn_mfma_f32_16x16x16f16(esh[t], edh1, e1, 0, 0, 0);
        e2 = __builtin_amdgcn_mfma_f32_16x16x16f16(esh[t], edh2, e2, 0, 0, 0);

        // perm sums (same order as R13-R19)
        float c0 = a0[0] + a1[1] + a2[2];   // (0,1,2) -> 6
        float c1 = a0[0] + a1[2] + a2[1];   // (0,2,1) -> 9
        float c2 = a0[1] + a1[0] + a2[2];   // (1,0,2) -> 18
        float c3 = a0[1] + a1[2] + a2[0];   // (1,2,0) -> 24
        float c4 = a0[2] + a1[0] + a2[1];   // (2,0,1) -> 33
        float c5 = a0[2] + a1[1] + a2[0];   // (2,1,0) -> 36

        float b1 = c0, b2 = -3.4e38f; int bpk = 6;
        if (c1 > b1) { b2 = b1; b1 = c1; bpk = 9;  } else if (c1 > b2) b2 = c1;
        if (c2 > b1) { b2 = b1; b1 = c2; bpk = 18; } else if (c2 > b2) b2 = c2;
        if (c3 > b1) { b2 = b1; b1 = c3; bpk = 24; } else if (c3 > b2) b2 = c3;
        if (c4 > b1) { b2 = b1; b1 = c4; bpk = 33; } else if (c4 > b2) b2 = c4;
        if (c5 > b1) { b2 = b1; b1 = c5; bpk = 36; } else if (c5 > b2) b2 = c5;

        const int a = (bpk >> 4) & 3, b = (bpk >> 2) & 3, cc = bpk & 3;

        float se0 = (a  == 0) ? e0[0] : ((a  == 1) ? e0[1] : e0[2]);
        float se1 = (b  == 0) ? e1[0] : ((b  == 1) ? e1[1] : e1[2]);
        float se2 = (cc == 0) ? e2[0] : ((cc == 1) ? e2[1] : e2[2]);
        float bestE = se0 + se1 + se2;

        float la = (a  == 0) ? tb0[0] : ((a  == 1) ? tb0[1] : tb0[2]);
        float lb = (b  == 0) ? tb0[0] : ((b  == 1) ? tb0[1] : tb0[2]);
        float lc = (cc == 0) ? tb0[0] : ((cc == 1) ? tb0[1] : tb0[2]);
        float bestL = fmaf(lenN0, la, fmaf(lenN1, lb, lenN2 * lc));

        float C01 = tb0[3], C02 = tb1[0], C12 = tb1[1];
        int sca = cc + a, sab = a + b, sbc = b + cc;          // in {1,2,3}
        float Cca = (sca == 1) ? C01 : ((sca == 2) ? C02 : C12);
        float Cab = (sab == 1) ? C01 : ((sab == 2) ? C02 : C12);
        float Cbc = (sbc == 1) ? C01 : ((sbc == 2) ? C02 : C12);
        float bestA = fmaf(angN0, Cca, fmaf(angN1, Cab, angN2 * Cbc));

        // atan(1/d) - pi/2 = -atan(d) for d>=0: squares equal
        float dist = rp + tb2[2] - 2.0f * b1;
        float t3v = fast_atan_abs(dist);
        float t1v = fast_atan_abs(lenN_sq + tb1[3] - 2.0f * bestL);
        float t2v = fast_atan_abs(angN_sq + tb1[2] - 2.0f * bestA);
        float t4v = fast_atan_abs(xfsq    + tb2[1] - 2.0f * accC[t]);
        float t5v = fast_atan_abs(edsq    + tb2[0] - 2.0f * bestE);

        float h = t1v*t1v + t2v*t2v + t3v*t3v + t4v*t4v + t5v*t5v;

        if (ok) {
            size_t idx = (size_t)l_t * N + n_j;
            out[idx] = fast_atan_recip(h);
            if (b1 - b2 <= TIE_THR) {
                int slot = atomicAdd(wl_cnt, 1);
                if (slot < wl_cap) wl[slot] = (int)idx;
            }
        }
    }
}

// -------- Kernel A2: full recompute for tie cells (fp64 ranking) -----------
__global__ __launch_bounds__(256)
void setconvA2(const float* __restrict__ x_neighbor,
               const float* __restrict__ x_support,
               const float* __restrict__ x_focal,
               const float* __restrict__ p_focal,
               const float* __restrict__ p_neighbor,
               const float* __restrict__ edge_nei,
               const float* __restrict__ x_center,
               const float* __restrict__ edge_sup,
               const float* __restrict__ table,
               float* __restrict__ out,
               const int* __restrict__ wl_cnt,
               const int* __restrict__ wl,
               int wl_cap, int N)
{
    int cnt = *wl_cnt; if (cnt > wl_cap) cnt = wl_cap;
    const int stride = gridDim.x * blockDim.x;
    for (int i = blockIdx.x * blockDim.x + threadIdx.x; i < cnt; i += stride) {
        const int idx = wl[i];
        const int l = idx / N;
        const int n = idx - l * N;
        const float* xn = x_neighbor + (size_t)n * 96;
        const float* xs = x_support  + (size_t)l * 96;

        double dr[3][3] = {{0,0,0},{0,0,0},{0,0,0}};
        double nei = 0.0;
        for (int f = 0; f < 32; ++f) {
            double a0 = (double)xn[f], a1 = (double)xn[32 + f], a2 = (double)xn[64 + f];
            double b0 = (double)xs[f], b1 = (double)xs[32 + f], b2 = (double)xs[64 + f];
            dr[0][0] += a0 * b0; dr[0][1] += a0 * b1; dr[0][2] += a0 * b2;
            dr[1][0] += a1 * b0; dr[1][1] += a1 * b1; dr[1][2] += a1 * b2;
            dr[2][0] += a2 * b0; dr[2][1] += a2 * b1; dr[2][2] += a2 * b2;
            nei += a0 * a0 + a1 * a1 + a2 * a2;
        }
        double d0 = dr[0][0] + dr[1][1] + dr[2][2];
        double d1 = dr[0][0] + dr[1][2] + dr[2][1];
        double d2 = dr[0][1] + dr[1][0] + dr[2][2];
        double d3 = dr[0][1] + dr[1][2] + dr[2][0];
        double d4 = dr[0][2] + dr[1][0] + dr[2][1];
        double d5 = dr[0][2] + dr[1][1] + dr[2][0];
        double db = d0; int bpk = 6;
        if (d1 > db) { db = d1; bpk = 9;  }
        if (d2 > db) { db = d2; bpk = 18; }
        if (d3 > db) { db = d3; bpk = 24; }
        if (d4 > db) { db = d4; bpk = 33; }
        if (d5 > db) { db = d5; bpk = 36; }
        const int a = (bpk >> 4) & 3, b = (bpk >> 2) & 3, c = bpk & 3;

        const float* tb = table + l * 16;
        float dist = (float)(nei + (double)tb[10] - 2.0 * db);
        float t3v = atanf(dist);

        const float* es = edge_sup + (size_t)l * 24;
        const float* ed = edge_nei + (size_t)n * 24;
        float er[3][3] = {{0,0,0},{0,0,0},{0,0,0}};
        for (int f = 0; f < 8; ++f) {
            float b0 = es[f], b1 = es[8 + f], b2 = es[16 + f];
            float a0 = ed[f], a1 = ed[8 + f], a2 = ed[16 + f];
            er[0][0] = fmaf(a0, b0, er[0][0]);
            er[0][1] = fmaf(a0, b1, er[0][1]);
            er[0][2] = fmaf(a0, b2, er[0][2]);
            er[1][0] = fmaf(a1, b0, er[1][0]);
            er[1][1] = fmaf(a1, b1, er[1][1]);
            er[1][2] = fmaf(a1, b2, er[1][2]);
            er[2][0] = fmaf(a2, b0, er[2][0]);
            er[2][1] = fmaf(a2, b1, er[2][1]);
            er[2][2] = fmaf(a2, b2, er[2][2]);
        }
        float edsq = 0.f;
        for (int f = 0; f < 24; ++f) edsq = fmaf(ed[f], ed[f], edsq);

        const float* xf = x_focal + (size_t)n * 32;
        const float* xc = x_center + (size_t)l * 32;
        float cdot = 0.f, xfsq = 0.f;
        for (int f = 0; f < 32; ++f) {
            cdot = fmaf(xf[f], xc[f], cdot);
            xfsq = fmaf(xf[f], xf[f], xfsq);
        }

        float pf0 = p_focal[(size_t)n*3+0], pf1 = p_focal[(size_t)n*3+1], pf2 = p_focal[(size_t)n*3+2];
        const float* pp = p_neighbor + (size_t)n * 9;
        float pr00=pp[0]-pf0, pr01=pp[1]-pf1, pr02=pp[2]-pf2;
        float pr10=pp[3]-pf0, pr11=pp[4]-pf1, pr12=pp[5]-pf2;
        float pr20=pp[6]-pf0, pr21=pp[7]-pf1, pr22=pp[8]-pf2;
        float lenN0 = sqrtf(pr00*pr00 + pr01*pr01 + pr02*pr02);
        float lenN1 = sqrtf(pr10*pr10 + pr11*pr11 + pr12*pr12);
        float lenN2 = sqrtf(pr20*pr20 + pr21*pr21 + pr22*pr22);
        float angN0 = (pr20*pr00 + pr21*pr01 + pr22*pr02) / fmaxf(lenN2*lenN0, 1e-8f);
        float angN1 = (pr00*pr10 + pr01*pr11 + pr02*pr12) / fmaxf(lenN0*lenN1, 1e-8f);
        float angN2 = (pr10*pr20 + pr11*pr21 + pr12*pr22) / fmaxf(lenN1*lenN2, 1e-8f);
        float angN_sq = angN0*angN0 + angN1*angN1 + angN2*angN2;
        float lenN_sq = lenN0*lenN0 + lenN1*lenN1 + lenN2*lenN2;

        float bestE = er[0][a] + er[1][b] + er[2][c];
        float nv[3] = {tb[0], tb[1], tb[2]};
        float bestL = fmaf(lenN0, nv[a], fmaf(lenN1, nv[b], lenN2 * nv[c]));
        float C01 = tb[3], C02 = tb[4], C12 = tb[5];
        int sca = c + a, sab = a + b, sbc = b + c;
        float Cca = (sca == 1) ? C01 : ((sca == 2) ? C02 : C12);
        float Cab = (sab == 1) ? C01 : ((sab == 2) ? C02 : C12);
        float Cbc = (sbc == 1) ? C01 : ((sbc == 2) ? C02 : C12);
        float bestA = fmaf(angN0, Cca, fmaf(angN1, Cab, angN2 * Cbc));

        float t1v = atanf(lenN_sq + tb[7] - 2.0f * bestL);
        float t2v = atanf(angN_sq + tb[6] - 2.0f * bestA);
        float t4v = atanf(xfsq    + tb[9] - 2.0f * cdot);
        float t5v = atanf(edsq    + tb[8] - 2.0f * bestE);

        float h = t1v*t1v + t2v*t2v + t3v*t3v + t4v*t4v + t5v*t5v;
        out[idx] = atanf(1.0f / h);
    }
}

extern "C" void kernel_launch(void* const* d_in, const int* in_sizes, int n_in,
                              void* d_out, int out_size, void* d_ws, size_t ws_size,
                              hipStream_t stream)
{
    const float* x_focal    = (const float*)d_in[0];
    const float* p_focal    = (const float*)d_in[1];
    const float* x_neighbor = (const float*)d_in[2];
    const float* p_neighbor = (const float*)d_in[3];
    const float* edge_nei   = (const float*)d_in[4];
    const float* x_center   = (const float*)d_in[5];
    const float* x_support  = (const float*)d_in[6];
    const float* edge_sup   = (const float*)d_in[7];
    const float* p_support  = (const float*)d_in[8];
    float* out = (float*)d_out;

    const int N = in_sizes[0] / 32;                // x_focal is (N, 32)

    // d_ws layout: [0,4096) table | [4096, 4096+32N) nscal | cnt | worklist
    float* table = (float*)d_ws;
    float* nscal = (float*)((char*)d_ws + 4096);
    size_t cnt_off = 4096 + (size_t)N * 32;
    cnt_off = (cnt_off + 15) & ~(size_t)15;
    int* wl_cnt = (int*)((char*)d_ws + cnt_off);
    int* wl     = (int*)((char*)d_ws + cnt_off + 16);
    long cap_l = ((long)ws_size - (long)cnt_off - 16) / 4;
    int wl_cap = cap_l < 0 ? 0 : (cap_l > 4000000 ? 4000000 : (int)cap_l);

    // 3 dispatches total (was 5: P, Pn, memset folded into PP)
    setconvPP<<<(N + 255) / 256, 256, 0, stream>>>(p_focal, p_neighbor,
                                                   x_support, edge_sup, x_center,
                                                   p_support, nscal, table, wl_cnt, N);

    dim3 gridF((N + 15) / 16, 4);
    setconvF<<<gridF, 64, 0, stream>>>(x_neighbor, x_support, x_focal,
                                       edge_nei, x_center, edge_sup,
                                       table, nscal, out, wl_cnt, wl, wl_cap, N);
    setconvA2<<<64, 256, 0, stream>>>(x_neighbor, x_support, x_focal, p_focal,
                                      p_neighbor, edge_nei, x_center, edge_sup,
                                      table, out, wl_cnt, wl, wl_cap, N);
}